// Round 14
// baseline (53.268 us; speedup 1.0000x reference)
//
#include <hip/hip_runtime.h>
#include <hip/hip_bf16.h>

#define NN 10000
#define NE 160000
#define NBT 16          // B*T = 2*8
#define CIN 15          // N_IN - 1
#define HPAD 128        // elems per bt-half: 8 t x 16 (c=15 is zero pad / dist slot)
#define BCAP 64         // bucket capacity (deg ~ Poisson(16), max ~40)
#define NOUT 32
#define ALPHA_F 0.2f

#define TRANS_BLKS 625  // 16 nodes per block
#define EDGE_BLKS  625  // 256 edges per block

__device__ __forceinline__ float bf2f(unsigned short u) {
    return __uint_as_float(((unsigned int)u) << 16);
}
__device__ __forceinline__ unsigned short f2bf(float f) {
    __hip_bfloat16 h = __float2bfloat16(f);
    return *(unsigned short*)&h;
}

// ---- zero cursor[NN]
__global__ __launch_bounds__(256) void zero_ws(int* __restrict__ p) {
    int i = blockIdx.x * 256 + threadIdx.x;
    if (i < NN) p[i] = 0;
}

// ---- prep: blocks [0,625): transpose+cast x -> xh[n][half][t][16] bf16 (c=15 pad=0)
//            blocks [625,1250): bucket binning, 8B payload {src|dist_bf16, w0|w1}
__global__ __launch_bounds__(256) void prep(const float* __restrict__ x,
                                            const int* __restrict__ edges,
                                            const float* __restrict__ dist,
                                            const float* __restrict__ dew,
                                            unsigned short* __restrict__ xh,
                                            int* __restrict__ cursor,
                                            int2* __restrict__ epay) {
    __shared__ float tile[NBT][16 * CIN];   // 15.36 KB
    int bid = blockIdx.x;
    int tid = threadIdx.x;
    if (bid < TRANS_BLKS) {
        int n0 = bid * 16;
        if (tid < 16 * CIN) {
#pragma unroll
            for (int bt = 0; bt < NBT; ++bt)
                tile[bt][tid] = x[((size_t)bt * NN + n0) * CIN + tid];
        }
        __syncthreads();
        for (int g = tid; g < 16 * 256; g += 256) {
            int ln = g >> 8;              // node within tile
            int r  = g & 255;             // elem within row
            int c  = r & 15;
            int bt = r >> 4;              // half*8 + t
            float v = (c < 15) ? tile[bt][ln * CIN + c] : 0.f;
            xh[(size_t)(n0 + ln) * 256 + r] = f2bf(v);
        }
    } else {
        int e = (bid - TRANS_BLKS) * 256 + tid;
        if (e < NE) {
            int2 ed = ((const int2*)edges)[e];          // {src, dst}
            float2 w = ((const float2*)dew)[e];         // {w0, w1}
            float d = dist[e];
            int pos = atomicAdd(&cursor[ed.y], 1);
            if (pos < BCAP) {
                unsigned int px = (unsigned int)ed.x | ((unsigned int)f2bf(d) << 16);
                unsigned int py = (unsigned int)f2bf(w.x) | ((unsigned int)f2bf(w.y) << 16);
                epay[ed.y * BCAP + pos] = make_int2((int)px, (int)py);
            }
        }
    }
}

// ---- fused: wave per (node, bt-half); XCD-pinned halves -> per-XCD xh working
//      set 2.56 MB (L2-resident). Bucket preload + readlane; dist-in-pad FMAs.
__global__ __launch_bounds__(256) void fused_node(const unsigned short* __restrict__ xh,
                                                  const int* __restrict__ cursor,
                                                  const int2* __restrict__ epay,
                                                  const float* __restrict__ dew,
                                                  const float* __restrict__ W,
                                                  const float* __restrict__ bias,
                                                  float* __restrict__ out) {
    __shared__ float s_xc[4][2][HPAD];     // [unit][head][t*16+c] = 4 KB

    const int tid = threadIdx.x;
    const int unit = tid >> 6;                       // 4 (node,half) per block
    const int lane = tid & 63;
    const int bid = blockIdx.x;
    const int hf = (bid & 7) >> 2;                   // batch b: XCDs 0-3 -> 0, 4-7 -> 1
    const int gidHalf = (bid >> 3) * 4 + (bid & 3);  // 0..2499
    const int n = gidHalf * 4 + unit;                // [0,10000)
    const int o = lane & 31;
    const int h = lane >> 5;
    const bool ispad = (lane & 7) == 7;    // this lane's elem1 is a t's channel-15 slot

    // per-lane W row (broadcast-cached; W is 2 KB) + bias — no LDS, no barrier
    float4 w0_ = *(const float4*)(W + o * 16);
    float4 w1_ = *(const float4*)(W + o * 16 + 4);
    float4 w2_ = *(const float4*)(W + o * 16 + 8);
    float4 w3_ = *(const float4*)(W + o * 16 + 12);
    float bo = bias[o];

    int deg = cursor[n];
    if (deg > BCAP) deg = BCAP;

    // 256B preload of bucket slots 0..31 (lanes 32-63 duplicate -> broadcast lines)
    int2 pay = epay[n * BCAP + (lane & 31)];

    // ---- gather: lane owns elems {2*lane, 2*lane+1} of this half's 128-elem row
    const char* xbase = (const char*)xh + hf * 256 + 4 * lane;
    float a00 = 0.f, a01 = 0.f, a10 = 0.f, a11 = 0.f;

    int dmain = deg > 32 ? 32 : deg;
#pragma unroll 8
    for (int k = 0; k < dmain; ++k) {
        int sx = __builtin_amdgcn_readlane(pay.x, k);     // {dist_bf16<<16 | src}
        int sw = __builtin_amdgcn_readlane(pay.y, k);     // {w1_bf16<<16 | w0_bf16}
        unsigned int u = *(const unsigned int*)(xbase + (size_t)((sx & 0xFFFF) << 9));
        float w0 = __uint_as_float((unsigned int)sw << 16);
        float w1 = __uint_as_float((unsigned int)sw & 0xFFFF0000u);
        float de = __uint_as_float((unsigned int)sx & 0xFFFF0000u);
        float x0 = __uint_as_float(u << 16);
        float x1 = ispad ? de : __uint_as_float(u & 0xFFFF0000u);  // dist-in-pad
        a00 += w0 * x0; a01 += w0 * x1;
        a10 += w1 * x0; a11 += w1 * x1;
    }
    if (deg > 32) {                        // rare (Poisson(16)): uniform tail
        int2 pay2 = epay[n * BCAP + 32 + (lane & 31)];
        for (int k = 32; k < deg; ++k) {
            int sx = __builtin_amdgcn_readlane(pay2.x, k - 32);
            int sw = __builtin_amdgcn_readlane(pay2.y, k - 32);
            unsigned int u = *(const unsigned int*)(xbase + (size_t)((sx & 0xFFFF) << 9));
            float w0 = __uint_as_float((unsigned int)sw << 16);
            float w1 = __uint_as_float((unsigned int)sw & 0xFFFF0000u);
            float de = __uint_as_float((unsigned int)sx & 0xFFFF0000u);
            float x0 = __uint_as_float(u << 16);
            float x1 = ispad ? de : __uint_as_float(u & 0xFFFF0000u);
            a00 += w0 * x0; a01 += w0 * x1;
            a10 += w1 * x0; a11 += w1 * x1;
        }
    }
    {   // self-loop (deterministic, never binned; dist=0 so pad stays real 0)
        unsigned int u = *(const unsigned int*)(xbase + ((size_t)n << 9));
        float w0 = dew[2 * (NE + n) + 0];
        float w1 = dew[2 * (NE + n) + 1];
        float x0 = __uint_as_float(u << 16);
        float x1 = __uint_as_float(u & 0xFFFF0000u);
        a00 += w0 * x0; a01 += w0 * x1;
        a10 += w1 * x0; a11 += w1 * x1;
    }
    *(float2*)&s_xc[unit][0][2 * lane] = make_float2(a00, a01);
    *(float2*)&s_xc[unit][1][2 * lane] = make_float2(a10, a11);

    // same-wave LDS RAW: drain LDS writes; no block barrier needed (wave-local data)
    asm volatile("s_waitcnt lgkmcnt(0)" ::: "memory");

    // ---- finalize: lane -> (h, o); loop t within this half; 4x ds_read_b128 per t.
    //      xt[15] holds dist_conv[n][h] (accumulated via pad slot) -> Wr[15]*v3.w
    {
        float Wr[16] = { w0_.x, w0_.y, w0_.z, w0_.w,
                         w1_.x, w1_.y, w1_.z, w1_.w,
                         w2_.x, w2_.y, w2_.z, w2_.w,
                         w3_.x, w3_.y, w3_.z, w3_.w };
        const float* xc = s_xc[unit][h];
        float prev = 0.f;
#pragma unroll
        for (int t = 0; t < 8; ++t) {
            const float* xt = xc + t * 16;
            float4 v0 = *(const float4*)(xt);
            float4 v1 = *(const float4*)(xt + 4);
            float4 v2 = *(const float4*)(xt + 8);
            float4 v3 = *(const float4*)(xt + 12);   // .w = dist_conv sum
            float y = bo;
            y += Wr[0]*v0.x + Wr[1]*v0.y + Wr[2]*v0.z + Wr[3]*v0.w;
            y += Wr[4]*v1.x + Wr[5]*v1.y + Wr[6]*v1.z + Wr[7]*v1.w;
            y += Wr[8]*v2.x + Wr[9]*v2.y + Wr[10]*v2.z + Wr[11]*v2.w;
            y += Wr[12]*v3.x + Wr[13]*v3.y + Wr[14]*v3.z + Wr[15]*v3.w;
            float v = (t == 0) ? y : (ALPHA_F * prev + (1.f - ALPHA_F) * y);
            float sg = 1.f / (1.f + __expf(-v));
            __builtin_nontemporal_store(sg,
                &out[(((size_t)(hf * 8 + t) * NN + n) * 2 + h) * NOUT + o]);
            prev = y;
        }
    }
}

extern "C" void kernel_launch(void* const* d_in, const int* in_sizes, int n_in,
                              void* d_out, int out_size, void* d_ws, size_t ws_size,
                              hipStream_t stream) {
    const float* x     = (const float*)d_in[0];
    // d_in[1] is T (scalar, always 8) — ignored
    const float* dew   = (const float*)d_in[2];
    const int*   edges = (const int*)d_in[3];
    const float* dist  = (const float*)d_in[4];
    const float* W     = (const float*)d_in[5];
    const float* bias  = (const float*)d_in[6];
    float* out = (float*)d_out;

    // workspace layout
    unsigned short* xh = (unsigned short*)d_ws;              // [NN][256] bf16 = 5.12 MB
    int2* epay   = (int2*)(xh + (size_t)NN * 256);           // [NN*64]*8B = 5.12 MB
    int* cursor  = (int*)(epay + (size_t)NN * BCAP);         // [NN]

    zero_ws<<<(NN + 255) / 256, 256, 0, stream>>>(cursor);
    prep<<<TRANS_BLKS + EDGE_BLKS, 256, 0, stream>>>(x, edges, dist, dew,
                                                     xh, cursor, epay);
    fused_node<<<5000, 256, 0, stream>>>(xh, cursor, epay, dew, W, bias, out);
}

// Round 15
// 48.664 us; speedup vs baseline: 1.0946x; 1.0946x over previous
//
#include <hip/hip_runtime.h>
#include <hip/hip_bf16.h>

#define NN 10000
#define NE 160000
#define NBT 16          // B*T = 2*8
#define CIN 15          // N_IN - 1
#define HPAD 128        // elems per bt-half: 8 t x 16 (c=15 is zero pad / dist slot)
#define BCAP 64         // bucket capacity (deg ~ Poisson(16), max ~40)
#define NOUT 32
#define ALPHA_F 0.2f

#define TRANS_BLKS 625  // 16 nodes per block
#define EDGE_BLKS  625  // 256 edges per block

__device__ __forceinline__ float bf2f(unsigned short u) {
    return __uint_as_float(((unsigned int)u) << 16);
}
__device__ __forceinline__ unsigned short f2bf(float f) {
    __hip_bfloat16 h = __float2bfloat16(f);
    return *(unsigned short*)&h;
}
__device__ __forceinline__ float bfl(unsigned int u) { return __uint_as_float(u << 16); }
__device__ __forceinline__ float bfh(unsigned int u) { return __uint_as_float(u & 0xFFFF0000u); }

// ---- zero cursor[NN]
__global__ __launch_bounds__(256) void zero_ws(int* __restrict__ p) {
    int i = blockIdx.x * 256 + threadIdx.x;
    if (i < NN) p[i] = 0;
}

// ---- prep: blocks [0,625): transpose+cast x -> xh[n][half][t][16] bf16 (c=15 pad=0)
//            blocks [625,1250): bucket binning, 8B payload {src|dist_bf16, w0|w1}
__global__ __launch_bounds__(256) void prep(const float* __restrict__ x,
                                            const int* __restrict__ edges,
                                            const float* __restrict__ dist,
                                            const float* __restrict__ dew,
                                            unsigned short* __restrict__ xh,
                                            int* __restrict__ cursor,
                                            int2* __restrict__ epay) {
    __shared__ float tile[NBT][16 * CIN];   // 15.36 KB
    int bid = blockIdx.x;
    int tid = threadIdx.x;
    if (bid < TRANS_BLKS) {
        int n0 = bid * 16;
        if (tid < 16 * CIN) {
#pragma unroll
            for (int bt = 0; bt < NBT; ++bt)
                tile[bt][tid] = x[((size_t)bt * NN + n0) * CIN + tid];
        }
        __syncthreads();
        for (int g = tid; g < 16 * 256; g += 256) {
            int ln = g >> 8;              // node within tile
            int r  = g & 255;             // elem within row
            int c  = r & 15;
            int bt = r >> 4;              // half*8 + t
            float v = (c < 15) ? tile[bt][ln * CIN + c] : 0.f;
            xh[(size_t)(n0 + ln) * 256 + r] = f2bf(v);
        }
    } else {
        int e = (bid - TRANS_BLKS) * 256 + tid;
        if (e < NE) {
            int2 ed = ((const int2*)edges)[e];          // {src, dst}
            float2 w = ((const float2*)dew)[e];         // {w0, w1}
            float d = dist[e];
            int pos = atomicAdd(&cursor[ed.y], 1);
            if (pos < BCAP) {
                unsigned int px = (unsigned int)ed.x | ((unsigned int)f2bf(d) << 16);
                unsigned int py = (unsigned int)f2bf(w.x) | ((unsigned int)f2bf(w.y) << 16);
                epay[ed.y * BCAP + pos] = make_int2((int)px, (int)py);
            }
        }
    }
}

// ---- pair-edge gather: half-wave per edge, lane owns 8 elems (uint4).
__device__ __forceinline__ void gather_node(
    int n, int deg, int2 pay, const int2* __restrict__ bucket,
    const char* __restrict__ xh_b, const float* __restrict__ dew,
    int lane, bool ispad, float* __restrict__ sdst /* [2][256] h-major */) {
    const int sub = lane & 31;
    const int half = lane >> 5;
    const char* xlane = xh_b + 16 * sub;
    float ac0[8] = {0,0,0,0,0,0,0,0};
    float ac1[8] = {0,0,0,0,0,0,0,0};

    int dmain = deg > 32 ? 32 : deg;
    int pairs = (dmain + 1) >> 1;
#pragma unroll 4
    for (int i = 0; i < pairs; ++i) {
        int sx = __shfl(pay.x, 2 * i, 32);        // half0: slot 2i, half1: slot 2i+1
        int sw = __shfl(pay.y, 2 * i, 32);
        bool val = (2 * i + half) < deg;
        unsigned int su = (unsigned int)sx & 0x3FFFu;          // sanitized (in-ws)
        uint4 u = *(const uint4*)(xlane + ((size_t)su << 9));
        float w0 = val ? bfh((unsigned int)sw << 16) : 0.f;    // w0 in low half
        float w1 = val ? bfh((unsigned int)sw) : 0.f;
        float de = bfh((unsigned int)sx);
        float x0 = bfl(u.x), x1 = bfh(u.x), x2 = bfl(u.y), x3 = bfh(u.y);
        float x4 = bfl(u.z), x5 = bfh(u.z), x6 = bfl(u.w);
        float x7 = ispad ? de : bfh(u.w);                      // dist-in-pad
        ac0[0]+=w0*x0; ac0[1]+=w0*x1; ac0[2]+=w0*x2; ac0[3]+=w0*x3;
        ac0[4]+=w0*x4; ac0[5]+=w0*x5; ac0[6]+=w0*x6; ac0[7]+=w0*x7;
        ac1[0]+=w1*x0; ac1[1]+=w1*x1; ac1[2]+=w1*x2; ac1[3]+=w1*x3;
        ac1[4]+=w1*x4; ac1[5]+=w1*x5; ac1[6]+=w1*x6; ac1[7]+=w1*x7;
    }
    if (deg > 32) {                                // rare (Poisson(16))
        int2 payB = bucket[32 + sub + half];
        int pairsB = (deg - 32 + 1) >> 1;
        for (int i = 0; i < pairsB; ++i) {
            int sx = __shfl(payB.x, 2 * i, 32);
            int sw = __shfl(payB.y, 2 * i, 32);
            bool val = (32 + 2 * i + half) < deg;
            unsigned int su = (unsigned int)sx & 0x3FFFu;
            uint4 u = *(const uint4*)(xlane + ((size_t)su << 9));
            float w0 = val ? bfh((unsigned int)sw << 16) : 0.f;
            float w1 = val ? bfh((unsigned int)sw) : 0.f;
            float de = bfh((unsigned int)sx);
            float x0 = bfl(u.x), x1 = bfh(u.x), x2 = bfl(u.y), x3 = bfh(u.y);
            float x4 = bfl(u.z), x5 = bfh(u.z), x6 = bfl(u.w);
            float x7 = ispad ? de : bfh(u.w);
            ac0[0]+=w0*x0; ac0[1]+=w0*x1; ac0[2]+=w0*x2; ac0[3]+=w0*x3;
            ac0[4]+=w0*x4; ac0[5]+=w0*x5; ac0[6]+=w0*x6; ac0[7]+=w0*x7;
            ac1[0]+=w1*x0; ac1[1]+=w1*x1; ac1[2]+=w1*x2; ac1[3]+=w1*x3;
            ac1[4]+=w1*x4; ac1[5]+=w1*x5; ac1[6]+=w1*x6; ac1[7]+=w1*x7;
        }
    }
    // combine the two half-wave partial sums (both halves end with full sums)
#pragma unroll
    for (int j = 0; j < 8; ++j) {
        ac0[j] += __shfl_xor(ac0[j], 32, 64);
        ac1[j] += __shfl_xor(ac1[j], 32, 64);
    }
    {   // self-loop post-combine (dist=0; memory pad is 0 so x7 stays clean)
        uint4 u = *(const uint4*)(xlane + ((size_t)n << 9));
        float w0 = dew[2 * (NE + n) + 0];
        float w1 = dew[2 * (NE + n) + 1];
        float xs[8] = { bfl(u.x), bfh(u.x), bfl(u.y), bfh(u.y),
                        bfl(u.z), bfh(u.z), bfl(u.w), bfh(u.w) };
#pragma unroll
        for (int j = 0; j < 8; ++j) { ac0[j] += w0 * xs[j]; ac1[j] += w1 * xs[j]; }
    }
    // lanes<32 write head0 slice, lanes>=32 write head1 (select via cndmask)
    float v0 = half ? ac1[0] : ac0[0], v1 = half ? ac1[1] : ac0[1];
    float v2 = half ? ac1[2] : ac0[2], v3 = half ? ac1[3] : ac0[3];
    float v4 = half ? ac1[4] : ac0[4], v5 = half ? ac1[5] : ac0[5];
    float v6 = half ? ac1[6] : ac0[6], v7 = half ? ac1[7] : ac0[7];
    float* dst = sdst + half * 256 + 8 * sub;
    *(float4*)(dst)     = make_float4(v0, v1, v2, v3);
    *(float4*)(dst + 4) = make_float4(v4, v5, v6, v7);
}

// ---- finalize one node from s_xc rows (reads are wave-broadcasts)
__device__ __forceinline__ void finalize_node(
    int n, const float* __restrict__ sdst, const float* __restrict__ Wr,
    float bo, int h, int o, float* __restrict__ out) {
    const float* xc = sdst + h * 256;
#pragma unroll
    for (int b = 0; b < 2; ++b) {
        float prev = 0.f;
#pragma unroll
        for (int t = 0; t < 8; ++t) {
            const float* xt = xc + b * HPAD + t * 16;
            float4 v0 = *(const float4*)(xt);
            float4 v1 = *(const float4*)(xt + 4);
            float4 v2 = *(const float4*)(xt + 8);
            float4 v3 = *(const float4*)(xt + 12);   // .w = dist_conv sum
            float y = bo;
            y += Wr[0]*v0.x + Wr[1]*v0.y + Wr[2]*v0.z + Wr[3]*v0.w;
            y += Wr[4]*v1.x + Wr[5]*v1.y + Wr[6]*v1.z + Wr[7]*v1.w;
            y += Wr[8]*v2.x + Wr[9]*v2.y + Wr[10]*v2.z + Wr[11]*v2.w;
            y += Wr[12]*v3.x + Wr[13]*v3.y + Wr[14]*v3.z + Wr[15]*v3.w;
            float v = (t == 0) ? y : (ALPHA_F * prev + (1.f - ALPHA_F) * y);
            float sg = 1.f / (1.f + __expf(-v));
            __builtin_nontemporal_store(sg,
                &out[(((size_t)(b * 8 + t) * NN + n) * 2 + h) * NOUT + o]);
            prev = y;
        }
    }
}

// ---- fused: 1250 blocks x 4 waves x 2 nodes (exactly one residency round).
__global__ __launch_bounds__(256) void fused_node(const unsigned short* __restrict__ xh,
                                                  const int* __restrict__ cursor,
                                                  const int2* __restrict__ epay,
                                                  const float* __restrict__ dew,
                                                  const float* __restrict__ W,
                                                  const float* __restrict__ bias,
                                                  float* __restrict__ out) {
    __shared__ float s_xc[4][2][2][256];   // [unit][node01][h][elem] = 16 KB

    const int tid = threadIdx.x;
    const int unit = tid >> 6;
    const int lane = tid & 63;
    const int o = lane & 31;
    const int h = lane >> 5;
    const bool ispad = (lane & 1);         // odd sub-lane owns a c=15 slot (elem7)
    const int wid = blockIdx.x * 4 + unit; // 0..4999
    const int n1 = wid * 2;
    const int n2 = n1 + 1;

    // issue both nodes' metadata/payload loads up front
    int deg1 = cursor[n1]; if (deg1 > BCAP) deg1 = BCAP;
    int deg2 = cursor[n2]; if (deg2 > BCAP) deg2 = BCAP;
    const int idx = (lane & 31) + (lane >> 5);      // half1 offset by +1 slot
    int2 pay1 = epay[n1 * BCAP + idx];
    int2 pay2 = epay[n2 * BCAP + idx];

    // per-lane W row + bias (broadcast-cached)
    float4 w0_ = *(const float4*)(W + o * 16);
    float4 w1_ = *(const float4*)(W + o * 16 + 4);
    float4 w2_ = *(const float4*)(W + o * 16 + 8);
    float4 w3_ = *(const float4*)(W + o * 16 + 12);
    float bo = bias[o];
    float Wr[16] = { w0_.x, w0_.y, w0_.z, w0_.w,  w1_.x, w1_.y, w1_.z, w1_.w,
                     w2_.x, w2_.y, w2_.z, w2_.w,  w3_.x, w3_.y, w3_.z, w3_.w };

    const char* xh_b = (const char*)xh;
    gather_node(n1, deg1, pay1, epay + n1 * BCAP, xh_b, dew, lane, ispad,
                &s_xc[unit][0][0][0]);
    gather_node(n2, deg2, pay2, epay + n2 * BCAP, xh_b, dew, lane, ispad,
                &s_xc[unit][1][0][0]);

    // same-wave LDS RAW: drain LDS writes (no block barrier; data is wave-local)
    asm volatile("s_waitcnt lgkmcnt(0)" ::: "memory");

    finalize_node(n1, &s_xc[unit][0][0][0], Wr, bo, h, o, out);
    finalize_node(n2, &s_xc[unit][1][0][0], Wr, bo, h, o, out);
}

extern "C" void kernel_launch(void* const* d_in, const int* in_sizes, int n_in,
                              void* d_out, int out_size, void* d_ws, size_t ws_size,
                              hipStream_t stream) {
    const float* x     = (const float*)d_in[0];
    // d_in[1] is T (scalar, always 8) — ignored
    const float* dew   = (const float*)d_in[2];
    const int*   edges = (const int*)d_in[3];
    const float* dist  = (const float*)d_in[4];
    const float* W     = (const float*)d_in[5];
    const float* bias  = (const float*)d_in[6];
    float* out = (float*)d_out;

    // workspace layout
    unsigned short* xh = (unsigned short*)d_ws;              // [NN][256] bf16 = 5.12 MB
    int2* epay   = (int2*)(xh + (size_t)NN * 256);           // [NN*64]*8B = 5.12 MB
    int* cursor  = (int*)(epay + (size_t)NN * BCAP);         // [NN]

    zero_ws<<<(NN + 255) / 256, 256, 0, stream>>>(cursor);
    prep<<<TRANS_BLKS + EDGE_BLKS, 256, 0, stream>>>(x, edges, dist, dew,
                                                     xh, cursor, epay);
    fused_node<<<1250, 256, 0, stream>>>(xh, cursor, epay, dew, W, bias, out);
}